// Round 21
// baseline (157.213 us; speedup 1.0000x reference)
//
#include <hip/hip_runtime.h>
#include <hip/hip_bf16.h>

#define NB 16384
#define ND 1024
#define NT 20
#define NC 100
#define NTILES_MAX 280         // 64-row tiles: sum ceil(cnt_t/64) <= 276
#define SPLITK 2               // K halves; last-arriver merges
#define STEPS 8                // K=512 per block, BK=64
#define ABUF 8192              // 64 rows x 64 bf16 x 2B
#define BBUF 14336             // 14 fragment blocks x 1KB
#define BUFB (ABUF + BBUF)     // 22528; x2 = 45056 -> 3 blocks/CU

typedef __bf16  bf16x8 __attribute__((ext_vector_type(8)));
typedef float   f32x4  __attribute__((ext_vector_type(4)));
typedef unsigned short ushort_t;

__device__ __forceinline__ unsigned int f2bf(float f) {
    unsigned int u = __builtin_bit_cast(unsigned int, f);
    u += 0x7FFFu + ((u >> 16) & 1u);   // RNE
    return u >> 16;
}
__device__ __forceinline__ unsigned long long pack4(float a, float b, float c, float d) {
    return (unsigned long long)f2bf(a)
         | ((unsigned long long)f2bf(b) << 16)
         | ((unsigned long long)f2bf(c) << 32)
         | ((unsigned long long)f2bf(d) << 48);
}

// async 16B/lane global->LDS; LDS dest = wave-uniform base + lane*16 (HW)
__device__ __forceinline__ void async_cp16(const void* g, void* l) {
    auto gp = reinterpret_cast<const __attribute__((address_space(1))) unsigned int*>(
        reinterpret_cast<unsigned long long>(g));
    auto lp = reinterpret_cast<__attribute__((address_space(3))) unsigned int*>(
        static_cast<unsigned int>(reinterpret_cast<unsigned long long>(l)));
    __builtin_amdgcn_global_load_lds(gp, lp, 16, 0, 0);
}

// ---------------- fused prep: wcvt (blocks 0..279) + bucket (block 280) -----
// R20-verified verbatim + cnt[] zeroing (tile semaphores, reset every call).

__global__ __launch_bounds__(1024) void prep_kernel(
    const float* __restrict__ W, ushort_t* __restrict__ Wf,
    const int* __restrict__ t, int* __restrict__ offsets,
    int* __restrict__ tiles, int* __restrict__ idx_list,
    int* __restrict__ cnt_sem)
{
    const int tid = threadIdx.x;
    if (blockIdx.x < 280) {
        int g = blockIdx.x * 1024 + tid;            // 286720 threads total
        int kg   = g & 127;
        int rest = g >> 7;
        int c    = rest % 112;
        int task = rest / 112;
        unsigned long long u0 = 0, u1 = 0;
        if (c < NC) {
            const float* p = W + ((size_t)(task * NC + c)) * ND + kg * 8;
            float4 a = *(const float4*)p;
            float4 b = *(const float4*)(p + 4);
            u0 = pack4(a.x, a.y, a.z, a.w);
            u1 = pack4(b.x, b.y, b.z, b.w);
        }
        size_t dst = (((size_t)task * 32 + (kg >> 2)) * 7 + (c >> 4)) * 512
                   + (size_t)((c & 15) | ((kg & 3) << 4)) * 8;
        *(unsigned long long*)(Wf + dst)     = u0;
        *(unsigned long long*)(Wf + dst + 4) = u1;
        return;
    }
    __shared__ int h[NT], off[NT + 1], cur[NT], tb[NT + 1];
    if (tid < NT) h[tid] = 0;
    if (tid < NTILES_MAX) cnt_sem[tid] = 0;          // reset tile semaphores
    __syncthreads();
    const int4* t4 = (const int4*)t;
    int4 v[4];
#pragma unroll
    for (int k = 0; k < 4; ++k) v[k] = t4[tid + k * 1024];
#pragma unroll
    for (int k = 0; k < 4; ++k) {
        atomicAdd(&h[v[k].x], 1); atomicAdd(&h[v[k].y], 1);
        atomicAdd(&h[v[k].z], 1); atomicAdd(&h[v[k].w], 1);
    }
    __syncthreads();
    if (tid == 0) {
        int acc = 0, tv = 0;
        for (int i = 0; i < NT; ++i) {
            off[i] = acc; cur[i] = acc; tb[i] = tv;
            acc += h[i]; tv += (h[i] + 63) >> 6;
        }
        off[NT] = acc; tb[NT] = tv;
    }
    __syncthreads();
    if (tid <= NT) offsets[tid] = off[tid];
    const int ntiles = tb[NT];
    if (tid < NTILES_MAX) {
        int e = -1;
        if (tid < ntiles) {
            int task = 0;
            while (tb[task + 1] <= tid) ++task;
            e = (task << 16) | (tid - tb[task]);
        }
        tiles[tid] = e;
    }
#pragma unroll
    for (int k = 0; k < 4; ++k) {
        int base = (tid + k * 1024) * 4;
        idx_list[atomicAdd(&cur[v[k].x], 1)] = base;
        idx_list[atomicAdd(&cur[v[k].y], 1)] = base + 1;
        idx_list[atomicAdd(&cur[v[k].z], 1)] = base + 2;
        idx_list[atomicAdd(&cur[v[k].w], 1)] = base + 3;
    }
}

// ---------------- grouped GEMM: M=64, split-K=2, fused semaphore combine ----
// R20-verified kernel (XCD swizzle, bf16-A reg-staged, counted vmcnt) with
// the finalize fused: both kq blocks store partials; last-arriver (per-tile
// atomic counter) merges other partial + own acc + bias -> d_out. Float add
// is commutative -> bitwise-deterministic regardless of arrival order.

__global__ __launch_bounds__(256, 3) void gemm_kernel(
    const float* __restrict__ x, const ushort_t* __restrict__ Wfrag,
    const float* __restrict__ bias, const int* __restrict__ offsets,
    const int* __restrict__ tiles, const int* __restrict__ idx_list,
    float* __restrict__ p0, float* __restrict__ p1,
    int* __restrict__ cnt_sem, float* __restrict__ outF)
{
    __shared__ __align__(16) char lds[2 * BUFB];   // [Al0 Bl0][Al1 Bl1]
    __shared__ int sOld;
    // T1: chunked XCD swizzle (gridDim.x 560 % 8 == 0 -> bijective)
    const int nwg  = NTILES_MAX * SPLITK;
    const int bidL = (blockIdx.x & 7) * (nwg >> 3) + (blockIdx.x >> 3);
    const int ent = tiles[bidL >> 1];
    if (ent < 0) return;
    const int kq   = bidL & 1;
    const int task = ent >> 16;
    const int m0   = (ent & 0xffff) << 6;
    const int seg  = offsets[task];
    const int cnt  = offsets[task + 1] - seg;

    const int tid  = threadIdx.x;
    const int wid  = tid >> 6;
    const int lane = tid & 63;
    const int csel = lane & 15;
    const int q    = lane >> 4;

    // epilogue row ids first (older vmcnt entries = conservative-safe)
    int oi[4];
#pragma unroll
    for (int rr = 0; rr < 4; ++rr) {
        int gm = m0 + wid * 16 + q * 4 + rr;
        oi[rr] = (gm < cnt) ? idx_list[seg + gm] : -1;
    }

    // A sources: instr jj covers rows wid*16 + jj*4 + q, cols csel*4..+4
    const float* srcA[4];
#pragma unroll
    for (int jj = 0; jj < 4; ++jj) {
        int row = wid * 16 + jj * 4 + q;
        int sr  = m0 + row; if (sr > cnt - 1) sr = cnt - 1;
        srcA[jj] = x + (size_t)idx_list[seg + sr] * ND + kq * 512 + csel * 4;
    }
    // B staging: fragment-packed, lane-linear; wave w slots {w, w+4, w+8, w+12}
    const ushort_t* srcB = Wfrag + ((size_t)(task * 32 + kq * 16) * 7) * 512 + lane * 8;
    int bii[4];
#pragma unroll
    for (int jj = 0; jj < 4; ++jj) {
        int i = wid + 4 * jj;
        bii[jj] = (i < 14) ? i : (i - 14);   // 2 dup stages: identical data, benign
    }

    float4 aR[2][4];
    auto ISSUE_A = [&](int s, int set) {
#pragma unroll
        for (int jj = 0; jj < 4; ++jj)
            aR[set][jj] = *(const float4*)(srcA[jj] + s * 64);
    };
    auto ISSUE_B = [&](int s, char* Bl) {
#pragma unroll
        for (int jj = 0; jj < 4; ++jj)
            async_cp16(srcB + (size_t)(s * 14 + bii[jj]) * 512, Bl + bii[jj] * 1024);
    };
    auto WRITE_A = [&](int set, char* Al) {
#pragma unroll
        for (int jj = 0; jj < 4; ++jj) {
            int r = wid * 16 + jj * 4 + q;
            unsigned off = (unsigned)(r * 128 + ((csel * 8) ^ ((r & 7) << 4)));
            float4 v = aR[set][jj];
            *(unsigned long long*)(Al + off) = pack4(v.x, v.y, v.z, v.w);
        }
    };

    f32x4 acc[7] = {};
    const int rowA = wid * 16 + csel;
    const unsigned swzA = (unsigned)((rowA & 7) << 4);

    auto COMPUTE = [&](const char* buf) {
        const char* Ar = buf + rowA * 128;
        const char* Bl = buf + ABUF;
#pragma unroll
        for (int kkb = 0; kkb < 2; ++kkb) {
            bf16x8 af = *(const bf16x8*)(Ar + (((unsigned)(kkb * 64 + q * 16)) ^ swzA));
#pragma unroll
            for (int f = 0; f < 7; ++f) {
                bf16x8 bf = *(const bf16x8*)(Bl + (kkb * 7 + f) * 1024 + lane * 16);
                acc[f] = __builtin_amdgcn_mfma_f32_16x16x32_bf16(af, bf, acc[f], 0, 0, 0);
            }
        }
    };

    char* buf0 = lds;
    char* buf1 = lds + BUFB;

    // prologue: issue A0,B0,A1,B1 (16 VMEM/wave)
    ISSUE_A(0, 0); ISSUE_B(0, buf0 + ABUF);
    ISSUE_A(1, 1); ISSUE_B(1, buf1 + ABUF);
    asm volatile("s_waitcnt vmcnt(12)" ::: "memory");   // A0 regs arrived
    __builtin_amdgcn_sched_barrier(0);
    WRITE_A(0, buf0);
    asm volatile("s_waitcnt vmcnt(8)" ::: "memory");    // B0 landed
    __builtin_amdgcn_sched_barrier(0);
    asm volatile("s_waitcnt lgkmcnt(0)" ::: "memory");  // my A0 ds_writes done
    __builtin_amdgcn_s_barrier();                       // block-wide ready

#pragma unroll
    for (int s = 0; s < STEPS; ++s) {
        COMPUTE((s & 1) ? buf1 : buf0);
        if (s == STEPS - 1) break;
        asm volatile("s_waitcnt lgkmcnt(0)" ::: "memory");   // my buf-s reads done
        __builtin_amdgcn_sched_barrier(0);
        __builtin_amdgcn_s_barrier();                        // all buf-s reads done
        // stage phase
        asm volatile("s_waitcnt vmcnt(4)" ::: "memory");     // A(s+1) regs arrived
        __builtin_amdgcn_sched_barrier(0);
        WRITE_A((s + 1) & 1, (s & 1) ? buf0 : buf1);         // into buf (s+1)&1
        if (s < STEPS - 2) {
            ISSUE_A(s + 2, s & 1);                           // reuse set s&1
            ISSUE_B(s + 2, ((s & 1) ? buf1 : buf0) + ABUF);  // refill buf s&1
            asm volatile("s_waitcnt vmcnt(8)" ::: "memory"); // B(s+1) landed
        } else {
            asm volatile("s_waitcnt vmcnt(0)" ::: "memory"); // B(s+1) landed
        }
        __builtin_amdgcn_sched_barrier(0);
        asm volatile("s_waitcnt lgkmcnt(0)" ::: "memory");   // my A ds_writes done
        __builtin_amdgcn_s_barrier();                        // next buf ready
    }

    // ---- epilogue: write my partial, then last-arriver merges ----
    float* __restrict__ myP = kq ? p1 : p0;
#pragma unroll
    for (int f = 0; f < 7; ++f) {
        int cg = f * 16 + csel;
        if (cg < NC) {
#pragma unroll
            for (int rr = 0; rr < 4; ++rr)
                if (oi[rr] >= 0)
                    myP[(size_t)oi[rr] * NC + cg] = acc[f][rr];
        }
    }
    __threadfence();                         // release: my partial visible
    __syncthreads();                         // all threads fenced
    if (tid == 0) sOld = atomicAdd(&cnt_sem[bidL >> 1], 1);
    __syncthreads();
    if (sOld == 1) {                         // I'm the last arriver: merge
        __threadfence();                     // acquire: other partial visible
        const float* __restrict__ otP = kq ? p0 : p1;
#pragma unroll
        for (int f = 0; f < 7; ++f) {
            int cg = f * 16 + csel;
            if (cg < NC) {
                float bv = bias[task * NC + cg];
#pragma unroll
                for (int rr = 0; rr < 4; ++rr)
                    if (oi[rr] >= 0) {
                        size_t off = (size_t)oi[rr] * NC + cg;
                        outF[off] = acc[f][rr] + otP[off] + bv;
                    }
            }
        }
    }
}

// ---------------- launch ----------------

extern "C" void kernel_launch(void* const* d_in, const int* in_sizes, int n_in,
                              void* d_out, int out_size, void* d_ws, size_t ws_size,
                              hipStream_t stream) {
    const float* x    = (const float*)d_in[0];
    const int*   t    = (const int*)d_in[1];
    const float* W    = (const float*)d_in[2];
    const float* bias = (const float*)d_in[3];

    char* ws = (char*)d_ws;
    int* offsets  = (int*)ws;                    // 21 ints  @ 0
    int* tiles    = (int*)(ws + 128);            // 280 ints -> ends 1248
    int* cnt_sem  = (int*)(ws + 2048);           // 280 ints -> ends 3168
    int* idx_list = (int*)(ws + 4352);           // 16384 ints -> ends 69888
    ushort_t* Wf  = (ushort_t*)(ws + 69888);     // 4,587,520 B -> ends 4,657,408
    const size_t PART = (size_t)NB * NC * sizeof(float);   // 6,553,600
    float* p0 = (float*)(ws + 4657408);
    float* p1 = (float*)(ws + 4657408 + PART);

    prep_kernel<<<281, 1024, 0, stream>>>(W, Wf, t, offsets, tiles, idx_list, cnt_sem);
    gemm_kernel<<<NTILES_MAX * SPLITK, 256, 0, stream>>>(
        x, Wf, bias, offsets, tiles, idx_list, p0, p1, cnt_sem, (float*)d_out);
}

// Round 22
// 39.191 us; speedup vs baseline: 4.0115x; 4.0115x over previous
//
#include <hip/hip_runtime.h>
#include <hip/hip_bf16.h>

#define NB 16384
#define ND 1024
#define NT 20
#define NC 100
#define NTILES_MAX 280         // 64-row tiles: sum ceil(cnt_t/64) <= 276
#define SPLITK 2               // K halves; kq=0 -> d_out, kq=1 -> ws partial
#define STEPS 8                // K=512 per block, BK=64
#define ABUF 8192              // 64 rows x 64 bf16 x 2B
#define BBUF 14336             // 14 fragment blocks x 1KB
#define BUFB (ABUF + BBUF)     // 22528; x2 = 45056 -> 3 blocks/CU

typedef __bf16  bf16x8 __attribute__((ext_vector_type(8)));
typedef float   f32x4  __attribute__((ext_vector_type(4)));
typedef unsigned short ushort_t;

__device__ __forceinline__ unsigned int f2bf(float f) {
    unsigned int u = __builtin_bit_cast(unsigned int, f);
    u += 0x7FFFu + ((u >> 16) & 1u);   // RNE
    return u >> 16;
}
__device__ __forceinline__ unsigned long long pack4(float a, float b, float c, float d) {
    return (unsigned long long)f2bf(a)
         | ((unsigned long long)f2bf(b) << 16)
         | ((unsigned long long)f2bf(c) << 32)
         | ((unsigned long long)f2bf(d) << 48);
}

// async 16B/lane global->LDS; LDS dest = wave-uniform base + lane*16 (HW)
__device__ __forceinline__ void async_cp16(const void* g, void* l) {
    auto gp = reinterpret_cast<const __attribute__((address_space(1))) unsigned int*>(
        reinterpret_cast<unsigned long long>(g));
    auto lp = reinterpret_cast<__attribute__((address_space(3))) unsigned int*>(
        static_cast<unsigned int>(reinterpret_cast<unsigned long long>(l)));
    __builtin_amdgcn_global_load_lds(gp, lp, 16, 0, 0);
}

// ---------------- fused prep: wcvt (blocks 0..279) + bucket (block 280) -----
// R17/R19/R20-verified verbatim (64-row tile table).

__global__ __launch_bounds__(1024) void prep_kernel(
    const float* __restrict__ W, ushort_t* __restrict__ Wf,
    const int* __restrict__ t, int* __restrict__ offsets,
    int* __restrict__ tiles, int* __restrict__ idx_list)
{
    const int tid = threadIdx.x;
    if (blockIdx.x < 280) {
        int g = blockIdx.x * 1024 + tid;            // 286720 threads total
        int kg   = g & 127;
        int rest = g >> 7;
        int c    = rest % 112;
        int task = rest / 112;
        unsigned long long u0 = 0, u1 = 0;
        if (c < NC) {
            const float* p = W + ((size_t)(task * NC + c)) * ND + kg * 8;
            float4 a = *(const float4*)p;
            float4 b = *(const float4*)(p + 4);
            u0 = pack4(a.x, a.y, a.z, a.w);
            u1 = pack4(b.x, b.y, b.z, b.w);
        }
        size_t dst = (((size_t)task * 32 + (kg >> 2)) * 7 + (c >> 4)) * 512
                   + (size_t)((c & 15) | ((kg & 3) << 4)) * 8;
        *(unsigned long long*)(Wf + dst)     = u0;
        *(unsigned long long*)(Wf + dst + 4) = u1;
        return;
    }
    __shared__ int h[NT], off[NT + 1], cur[NT], tb[NT + 1];
    if (tid < NT) h[tid] = 0;
    __syncthreads();
    const int4* t4 = (const int4*)t;
    int4 v[4];
#pragma unroll
    for (int k = 0; k < 4; ++k) v[k] = t4[tid + k * 1024];
#pragma unroll
    for (int k = 0; k < 4; ++k) {
        atomicAdd(&h[v[k].x], 1); atomicAdd(&h[v[k].y], 1);
        atomicAdd(&h[v[k].z], 1); atomicAdd(&h[v[k].w], 1);
    }
    __syncthreads();
    if (tid == 0) {
        int acc = 0, tv = 0;
        for (int i = 0; i < NT; ++i) {
            off[i] = acc; cur[i] = acc; tb[i] = tv;
            acc += h[i]; tv += (h[i] + 63) >> 6;
        }
        off[NT] = acc; tb[NT] = tv;
    }
    __syncthreads();
    if (tid <= NT) offsets[tid] = off[tid];
    const int ntiles = tb[NT];
    if (tid < NTILES_MAX) {
        int e = -1;
        if (tid < ntiles) {
            int task = 0;
            while (tb[task + 1] <= tid) ++task;
            e = (task << 16) | (tid - tb[task]);
        }
        tiles[tid] = e;
    }
#pragma unroll
    for (int k = 0; k < 4; ++k) {
        int base = (tid + k * 1024) * 4;
        idx_list[atomicAdd(&cur[v[k].x], 1)] = base;
        idx_list[atomicAdd(&cur[v[k].y], 1)] = base + 1;
        idx_list[atomicAdd(&cur[v[k].z], 1)] = base + 2;
        idx_list[atomicAdd(&cur[v[k].w], 1)] = base + 3;
    }
}

// ---------------- grouped GEMM: M=64, split-K=2, bf16-A, XCD-swizzled -------
// R20-verified verbatim: R17 staging/vmcnt skeleton + T1 chunked XCD swizzle
// (grid 560 % 8 == 0 -> bijective); same-task Wf panels become own-L2 hits.

__global__ __launch_bounds__(256, 3) void gemm_kernel(
    const float* __restrict__ x, const ushort_t* __restrict__ Wfrag,
    const int* __restrict__ offsets, const int* __restrict__ tiles,
    const int* __restrict__ idx_list, float* __restrict__ out0,
    float* __restrict__ out1)
{
    __shared__ __align__(16) char lds[2 * BUFB];   // [Al0 Bl0][Al1 Bl1]
    // T1: chunked XCD swizzle (gridDim.x % 8 == 0 -> bijective)
    const int nwg  = NTILES_MAX * SPLITK;          // 560; 560/8 = 70 exact
    const int bidL = (blockIdx.x & 7) * (nwg >> 3) + (blockIdx.x >> 3);
    const int ent = tiles[bidL >> 1];
    if (ent < 0) return;
    const int kq   = bidL & 1;
    const int task = ent >> 16;
    const int m0   = (ent & 0xffff) << 6;
    const int seg  = offsets[task];
    const int cnt  = offsets[task + 1] - seg;

    const int tid  = threadIdx.x;
    const int wid  = tid >> 6;
    const int lane = tid & 63;
    const int csel = lane & 15;
    const int q    = lane >> 4;

    // epilogue row ids first (older vmcnt entries = conservative-safe)
    int oi[4];
#pragma unroll
    for (int rr = 0; rr < 4; ++rr) {
        int gm = m0 + wid * 16 + q * 4 + rr;
        oi[rr] = (gm < cnt) ? idx_list[seg + gm] : -1;
    }

    // A sources: instr jj covers rows wid*16 + jj*4 + q, cols csel*4..+4
    const float* srcA[4];
#pragma unroll
    for (int jj = 0; jj < 4; ++jj) {
        int row = wid * 16 + jj * 4 + q;
        int sr  = m0 + row; if (sr > cnt - 1) sr = cnt - 1;
        srcA[jj] = x + (size_t)idx_list[seg + sr] * ND + kq * 512 + csel * 4;
    }
    // B staging: fragment-packed, lane-linear; wave w slots {w, w+4, w+8, w+12}
    const ushort_t* srcB = Wfrag + ((size_t)(task * 32 + kq * 16) * 7) * 512 + lane * 8;
    int bii[4];
#pragma unroll
    for (int jj = 0; jj < 4; ++jj) {
        int i = wid + 4 * jj;
        bii[jj] = (i < 14) ? i : (i - 14);   // 2 dup stages: identical data, benign
    }

    float4 aR[2][4];
    auto ISSUE_A = [&](int s, int set) {
#pragma unroll
        for (int jj = 0; jj < 4; ++jj)
            aR[set][jj] = *(const float4*)(srcA[jj] + s * 64);
    };
    auto ISSUE_B = [&](int s, char* Bl) {
#pragma unroll
        for (int jj = 0; jj < 4; ++jj)
            async_cp16(srcB + (size_t)(s * 14 + bii[jj]) * 512, Bl + bii[jj] * 1024);
    };
    auto WRITE_A = [&](int set, char* Al) {
#pragma unroll
        for (int jj = 0; jj < 4; ++jj) {
            int r = wid * 16 + jj * 4 + q;
            unsigned off = (unsigned)(r * 128 + ((csel * 8) ^ ((r & 7) << 4)));
            float4 v = aR[set][jj];
            *(unsigned long long*)(Al + off) = pack4(v.x, v.y, v.z, v.w);
        }
    };

    f32x4 acc[7] = {};
    const int rowA = wid * 16 + csel;
    const unsigned swzA = (unsigned)((rowA & 7) << 4);

    auto COMPUTE = [&](const char* buf) {
        const char* Ar = buf + rowA * 128;
        const char* Bl = buf + ABUF;
#pragma unroll
        for (int kkb = 0; kkb < 2; ++kkb) {
            bf16x8 af = *(const bf16x8*)(Ar + (((unsigned)(kkb * 64 + q * 16)) ^ swzA));
#pragma unroll
            for (int f = 0; f < 7; ++f) {
                bf16x8 bf = *(const bf16x8*)(Bl + (kkb * 7 + f) * 1024 + lane * 16);
                acc[f] = __builtin_amdgcn_mfma_f32_16x16x32_bf16(af, bf, acc[f], 0, 0, 0);
            }
        }
    };

    char* buf0 = lds;
    char* buf1 = lds + BUFB;

    // prologue: issue A0,B0,A1,B1 (16 VMEM/wave)
    ISSUE_A(0, 0); ISSUE_B(0, buf0 + ABUF);
    ISSUE_A(1, 1); ISSUE_B(1, buf1 + ABUF);
    asm volatile("s_waitcnt vmcnt(12)" ::: "memory");   // A0 regs arrived
    __builtin_amdgcn_sched_barrier(0);
    WRITE_A(0, buf0);
    asm volatile("s_waitcnt vmcnt(8)" ::: "memory");    // B0 landed
    __builtin_amdgcn_sched_barrier(0);
    asm volatile("s_waitcnt lgkmcnt(0)" ::: "memory");  // my A0 ds_writes done
    __builtin_amdgcn_s_barrier();                       // block-wide ready

#pragma unroll
    for (int s = 0; s < STEPS; ++s) {
        COMPUTE((s & 1) ? buf1 : buf0);
        if (s == STEPS - 1) break;
        asm volatile("s_waitcnt lgkmcnt(0)" ::: "memory");   // my buf-s reads done
        __builtin_amdgcn_sched_barrier(0);
        __builtin_amdgcn_s_barrier();                        // all buf-s reads done
        // stage phase
        asm volatile("s_waitcnt vmcnt(4)" ::: "memory");     // A(s+1) regs arrived
        __builtin_amdgcn_sched_barrier(0);
        WRITE_A((s + 1) & 1, (s & 1) ? buf0 : buf1);         // into buf (s+1)&1
        if (s < STEPS - 2) {
            ISSUE_A(s + 2, s & 1);                           // reuse set s&1
            ISSUE_B(s + 2, ((s & 1) ? buf1 : buf0) + ABUF);  // refill buf s&1
            asm volatile("s_waitcnt vmcnt(8)" ::: "memory"); // B(s+1) landed
        } else {
            asm volatile("s_waitcnt vmcnt(0)" ::: "memory"); // B(s+1) landed
        }
        __builtin_amdgcn_sched_barrier(0);
        asm volatile("s_waitcnt lgkmcnt(0)" ::: "memory");   // my A ds_writes done
        __builtin_amdgcn_s_barrier();                        // next buf ready
    }

    // epilogue: direct store to per-kq buffer (bias added in finalize)
    float* __restrict__ outP = kq ? out1 : out0;
#pragma unroll
    for (int f = 0; f < 7; ++f) {
        int cg = f * 16 + csel;
        if (cg < NC) {
#pragma unroll
            for (int rr = 0; rr < 4; ++rr)
                if (oi[rr] >= 0)
                    outP[(size_t)oi[rr] * NC + cg] = acc[f][rr];
        }
    }
}

// ---------------- finalize: out = p0 + p1 + bias (R16/R17/R20-verified) -----

__global__ void finalize_kernel(float* __restrict__ o0, const float* __restrict__ o1,
                                const int* __restrict__ t, const float* __restrict__ bias) {
    int id = blockIdx.x * 256 + threadIdx.x;     // NB*NC/2 threads, float2 each
    float2 v0 = ((const float2*)o0)[id];
    float2 v1 = ((const float2*)o1)[id];
    int e0 = 2 * id;
    int oi = e0 / NC;
    int c  = e0 - oi * NC;                        // even, c+1 <= 99
    const float* brow = bias + t[oi] * NC;
    float2 o;
    o.x = v0.x + v1.x + brow[c];
    o.y = v0.y + v1.y + brow[c + 1];
    ((float2*)o0)[id] = o;
}

// ---------------- launch ----------------

extern "C" void kernel_launch(void* const* d_in, const int* in_sizes, int n_in,
                              void* d_out, int out_size, void* d_ws, size_t ws_size,
                              hipStream_t stream) {
    const float* x    = (const float*)d_in[0];
    const int*   t    = (const int*)d_in[1];
    const float* W    = (const float*)d_in[2];
    const float* bias = (const float*)d_in[3];

    char* ws = (char*)d_ws;
    int* offsets  = (int*)ws;                    // 21 ints  @ 0
    int* tiles    = (int*)(ws + 128);            // 280 ints -> ends 1248
    int* idx_list = (int*)(ws + 4352);           // 16384 ints -> ends 69888
    ushort_t* Wf  = (ushort_t*)(ws + 69888);     // 4,587,520 B -> ends 4,657,408
    float* out1   = (float*)(ws + 4657408);      // 6,553,600 B

    prep_kernel    <<<281, 1024, 0, stream>>>(W, Wf, t, offsets, tiles, idx_list);
    gemm_kernel    <<<NTILES_MAX * SPLITK, 256, 0, stream>>>(x, Wf, offsets, tiles,
                                                             idx_list, (float*)d_out,
                                                             out1);
    finalize_kernel<<<NB * NC / 512, 256, 0, stream>>>((float*)d_out, out1, t, bias);
}